// Round 6
// baseline (1393.937 us; speedup 1.0000x reference)
//
#include <hip/hip_runtime.h>
#include <math.h>

typedef __attribute__((ext_vector_type(4))) float f32x4;
typedef __attribute__((ext_vector_type(16))) float f32x16;
typedef __attribute__((ext_vector_type(8))) short bf16x8;

#define DI __device__ __forceinline__

DI unsigned short f32_to_bf16(float f) {
  unsigned int u = __float_as_uint(f);
  u += 0x7FFFu + ((u >> 16) & 1u);   // round-to-nearest-even
  return (unsigned short)(u >> 16);
}

static constexpr float kCode[16] = {
    -1.0f, -0.6961928009986877f, -0.5250730514526367f, -0.39491748809814453f,
    -0.28444138169288635f, -0.18477343022823334f, -0.09105003625154495f, 0.0f,
    0.07958029955625534f, 0.16093020141124725f, 0.24611230194568634f,
    0.33791524171829224f, 0.44070982933044434f, 0.5626170039176941f,
    0.7229568362236023f, 1.0f};

// ---------------------------------------------------------------------------
// NF4 quant-dequant (block=64): 16 lanes/block, float4/lane.
// ---------------------------------------------------------------------------
__global__ void __launch_bounds__(256) k_dequant_nf4(
    const float* __restrict__ in, unsigned short* __restrict__ out, int n4) {
  int i = blockIdx.x * 256 + threadIdx.x;
  if (i >= n4) return;
  f32x4 v = reinterpret_cast<const f32x4*>(in)[i];
  float am = fmaxf(fmaxf(fabsf(v.x), fabsf(v.y)), fmaxf(fabsf(v.z), fabsf(v.w)));
  am = fmaxf(am, __shfl_xor(am, 1));
  am = fmaxf(am, __shfl_xor(am, 2));
  am = fmaxf(am, __shfl_xor(am, 4));
  am = fmaxf(am, __shfl_xor(am, 8));
  float scale = (am == 0.0f) ? 1.0f : am;
  unsigned short o[4];
#pragma unroll
  for (int j = 0; j < 4; ++j) {
    float nv = ((const float*)&v)[j] / scale;
    int idx = 0;
#pragma unroll
    for (int b = 0; b < 15; ++b)
      idx += (nv > 0.5f * (kCode[b] + kCode[b + 1])) ? 1 : 0;
    o[j] = f32_to_bf16(kCode[idx] * am);
  }
  reinterpret_cast<ushort4*>(out)[i] = make_ushort4(o[0], o[1], o[2], o[3]);
}

__global__ void __launch_bounds__(256) k_f32_to_bf16(
    const float* __restrict__ in, unsigned short* __restrict__ out, int n4) {
  int i = blockIdx.x * 256 + threadIdx.x;
  if (i >= n4) return;
  f32x4 v = reinterpret_cast<const f32x4*>(in)[i];
  reinterpret_cast<ushort4*>(out)[i] =
      make_ushort4(f32_to_bf16(v.x), f32_to_bf16(v.y), f32_to_bf16(v.z), f32_to_bf16(v.w));
}

// ---------------------------------------------------------------------------
// GEMM helpers. BK=32, LDS rows = 64B. Element (r,k) at byte
//   r*64 + (((k>>3) ^ ((r>>1)&3))<<4) + (k&7)*2     (round-4 verified)
// Staging writes linearly via global_load_lds from pre-inverse-swizzled
// global sources: lane l of 1KB unit u covers row 16u+(l>>2),
// k-chunk (l&3)^((l>>3)&3).
// 32x32x16 fragment read: lane -> row (l&31), k-half (l>>5); for k-step kk,
// byte = row*64 + (((kk*2 + (l>>5)) ^ ((row>>1)&3))<<4)  -> conflict-free.
// ---------------------------------------------------------------------------
DI void gload16(const void* g, void* l) {
  __builtin_amdgcn_global_lo\
ad_lds(
      (const __attribute__((address_space(1))) void*)g,
      (__attribute__((address_space(3))) void*)l, 16, 0, 0);
}

DI void barrier_nodrain() {
  asm volatile("" ::: "memory");
  __builtin_amdgcn_s_barrier();
  asm volatile("" ::: "memory");
}

#define WAITV(N) asm volatile("s_waitcnt vmcnt(" #N ")" ::: "memory")

// ---------------------------------------------------------------------------
// Fused dual GEMM + SwiGLU. BM=256, BN=128, BK=32, 16 waves (4/SIMD):
// waves 0-7 gate (B1), 8-15 up (B2); pair p=w&7 owns 64x64 at
// (wr=p>>1, wc=p&1). MFMA 32x32x16 (2x2 frags, 8 MFMA/tile/wave).
// 4 LDS bufs x 32KB (A 16K | B1 8K | B2 8K), prefetch 3, counted vmcnt(4).
// Epilogue: f32x16 pairwise exchange (m-split) through dead staging LDS.
// ---------------------------------------------------------------------------
__global__ void __launch_bounds__(1024, 4) k_gemm_dual_swiglu(
    const unsigned short* __restrict__ X,
    const unsigned short* __restrict__ W1,
    const unsigned short* __restrict__ W2,
    unsigned short* __restrict__ H) {
  constexpr int K = 4096, N = 11008, NK = K / 32;
  __shared__ char ldsb[131072];

  const int tid = threadIdx.x;
  const int w = tid >> 6, l = tid & 63;

  const int bid = blockIdx.x;               // 1376 = 8 * 172
  const int lt = (bid & 7) * 172 + (bid >> 3);
  const int mt = lt & 15, nt0 = lt >> 4;
  const int m0 = mt * 256, n0 = nt0 * 128;

  const int p = w & 7;
  const bool isGate = (w < 8);
  const int wr = p >> 1, wc = p & 1;

  // ---- staging: 32 1KB-units, 2 per wave (round-4 verified map) ----
  const int lrow = l >> 2;
  const int kc8 = (((l & 3) ^ ((l >> 3) & 3)) << 3);
  const unsigned short* g0;
  const unsigned short* g1;
  int ldst0;
  if (w < 8) {
    g0 = X + (size_t)(m0 + 32 * w + lrow) * K + kc8;
    g1 = X + (size_t)(m0 + 32 * w + 16 + lrow) * K + kc8;
    ldst0 = 2 * w * 1024;
  } else if (w < 12) {
    g0 = W1 + (size_t)(n0 + 32 * (w - 8) + lrow) * K + kc8;
    g1 = W1 + (size_t)(n0 + 32 * (w - 8) + 16 + lrow) * K + kc8;
    ldst0 = 16384 + (w - 8) * 2048;
  } else {
    g0 = W2 + (size_t)(n0 + 32 * (w - 12) + lrow) * K + kc8;
    g1 = W2 + (size_t)(n0 + 32 * (w - 12) + 16 + lrow) * K + kc8;
    ldst0 = 24576 + (w - 12) * 2048;
  }

  // ---- read bases (32x32 frags) ----
  const int la31 = l & 31, kb = l >> 5;
  const int sw = ((la31 >> 1) & 3);
  const int o0 = (kb ^ sw) << 4;        // k-step 0 slot
  const int o1 = o0 ^ 32;               // k-step 1 slot
  const char* rdA = ldsb + (wr * 64 + la31) * 64;                     // +mt*2048
  const char* rdB = ldsb + 16384 + (isGate ? 0 : 8192) + (wc * 64 + la31) * 64;

  f32x16 acc[2][2] = {};
  bf16x8 a[2][2], b[2][2];

  // prologue: stage tiles 0,1,2
  gload16(g0, ldsb + ldst0);                 gload16(g1, ldsb + ldst0 + 1024);
  gload16(g0 + 32, ldsb + 32768 + ldst0);    gload16(g1 + 32, ldsb + 32768 + ldst0 + 1024);
  gload16(g0 + 64, ldsb + 65536 + ldst0);    gload16(g1 + 64, ldsb + 65536 + ldst0 + 1024);
  const unsigned short* p0 = g0 + 96;
  const unsigned short* p1 = g1 + 96;
  WAITV(4);
  barrier_nodrain();

  for (int t = 0; t < NK; ++t) {
    const int bo = (t & 3) << 15;
    if (t + 3 < NK) {
      const int bs = ((t + 3) & 3) << 15;
      gload16(p0, ldsb + bs + ldst0);
      gload16(p1, ldsb + bs + ldst0 + 1024);
    }
    p0 += 32; p1 += 32;
#pragma unroll
    for (int m = 0; m < 2; ++m) {
      a[m][0] = *(const bf16x8*)(rdA + bo + m * 2048 + o0);
      a[m][1] = *(const bf16x8*)(rdA + bo + m * 2048 + o1);
    }
#pragma unroll
    for (int n = 0; n < 2; ++n) {
      b[n][0] = *(const bf16x8*)(rdB + bo + n * 2048 + o0);
      b[n][1] = *(const bf16x8*)(rdB + bo + n * 2048 + o1);
    }
    __builtin_amdgcn_s_setprio(1);
#pragma unroll
    for (int kk = 0; kk < 2; ++kk)
#pragma unroll
      for (int m = 0; m < 2; ++m)
#pragma unroll
        for (int n = 0; n < 2; ++n)
          acc[m][n] = __builtin_amdgcn_mfma_f32_32x32x16_bf16(a[m][kk], b[n][kk], acc[m][n], 0, 0, 0);
    __builtin_amdgcn_s_setprio(0);
    if (t + 3 < NK)      { WAITV(4); barrier_nodrain(); }
    else if (t + 2 < NK) { WAITV(2); barrier_nodrain(); }
    else if (t + 1 < NK) { WAITV(0); barrier_nodrain(); }
  }

  // ---- epilogue: gate/up pairwise exchange (m-split), SwiGLU, store ----
  barrier_nodrain();                 // staging LDS dead for all waves
  char* myx = ldsb + w * 8192;
  const char* px = ldsb + (w ^ 8) * 8192;
  // write the m-half I do NOT store (gate -> acc[1], up -> acc[0])
#pragma unroll
  for (int n = 0; n < 2; ++n)
#pragma unroll
    for (int q = 0; q < 4; ++q) {
      f32x4 v;
      if (isGate) {
#pragma unroll
        for (int jj = 0; jj < 4; ++jj) v[jj] = acc[1][n][4 * q + jj];
      } else {
#pragma unroll
        for (int jj = 0; jj < 4; ++jj) v[jj] = acc[0][n][4 * q + jj];
      }
      *(f32x4*)(myx + ((n * 4 + q) * 64 + l) * 16) = v;
    }
  barrier_nodrain();
  const int smt = isGate ? 0 : 1;    // m-half this wave stores
#pragma unroll
  for (int n = 0; n < 2; ++n)
#pragma unroll
    for (int q = 0; q < 4; ++q) {
      f32x4 other = *(const f32x4*)(px + ((n * 4 + q) * 64 + l) * 16);
#pragma unroll
      for (int jj = 0; jj < 4; ++jj) {
        float mine;
        if (isGate) mine = acc[0][n][4 * q + jj];
        else        mine = acc[1][n][4 * q + jj];
        const float g_ = isGate ? mine : other[jj];
        const float u_ = isGate ? other[jj] : mine;
        const float s = g_ / (1.0f + expf(-g_));
        const int row = m0 + wr * 64 + smt * 32 + jj + 8 * q + 4 * kb;
        const int col = n0 + wc * 64 + n * 32 + la31;
        H[(size_t)row * N + col] = f32_to_bf16(s * u_);
      }
    }
}

// ---------------------------------------------------------------------------
// Output GEMM. BM=BN=256, BK=32, 16 waves (4M x 4N), per-wave 64x64 via
// 32x32x16 MFMA. 4 LDS bufs x 32KB (A 16K | B 16K), prefetch 3, vmcnt(4).
// ---------------------------------------------------------------------------
__global__ void __launch_bounds__(1024, 4) k_gemm_out(
    const unsigned short* __restrict__ Hm,
    const unsigned short* __restrict__ W3,
    float* __restrict__ Out) {
  constexpr int K = 11008, N = 4096, NK = K / 32;
  __shared__ char ldsb[131072];

  const int tid = threadIdx.x;
  const int w = tid >> 6, l = tid & 63;

  const int bid = blockIdx.x;              // 256 = 8 * 32
  const int lt = (bid & 7) * 32 + (bid >> 3);
  const int mt = lt & 15, nt0 = lt >> 4;
  const int m0 = mt * 256, n0 = nt0 * 256;

  const int wr = w >> 2, wc = w & 3;

  const int lrow = l >> 2;
  const int kc8 = (((l & 3) ^ ((l >> 3) & 3)) << 3);
  const unsigned short* g0;
  const unsigned short* g1;
  int ldst0;
  if (w < 8) {
    g0 = Hm + (size_t)(m0 + 32 * w + lrow) * K + kc8;
    g1 = Hm + (size_t)(m0 + 32 * w + 16 + lrow) * K + kc8;
    ldst0 = 2 * w * 1024;
  } else {
    g0 = W3 + (size_t)(n0 + 32 * (w - 8) + lrow) * K + kc8;
    g1 = W3 + (size_t)(n0 + 32 * (w - 8) + 16 + lrow) * K + kc8;
    ldst0 = 16384 + (w - 8) * 2048;
  }

  const int la31 = l & 31, kb = l >> 5;
  const int sw = ((la31 >> 1) & 3);
  const int o0 = (kb ^ sw) << 4;
  const int o1 = o0 ^ 32;
  const char* rdA = ldsb + (wr * 64 + la31) * 64;
  const char* rdB = ldsb + 16384 + (wc * 64 + la31) * 64;

  f32x16 acc[2][2] = {};
  bf16x8 a[2][2], b[2][2];

  gload16(g0, ldsb + ldst0);                 gload16(g1, ldsb + ldst0 + 1024);
  gload16(g0 + 32, ldsb + 32768 + ldst0);    gload16(g1 + 32, ldsb + 32768 + ldst0 + 1024);
  gload16(g0 + 64, ldsb + 65536 + ldst0);    gload16(g1 + 64, ldsb + 65536 + ldst0 + 1024);
  const unsigned short* p0 = g0 + 96;
  const unsigned short* p1 = g1 + 96;
  WAITV(4);
  barrier_nodrain();

  for (int t = 0; t < NK; ++t) {
    const int bo = (t & 3) << 15;
    if (t + 3 < NK) {
      const int bs = ((t + 3) & 3) << 15;
      gload16(p0, ldsb + bs + ldst0);
      gload16(p1, ldsb + bs + ldst0 + 1024);
    }
    p0 += 32; p1 += 32;
#pragma unroll
    for (int m = 0; m < 2; ++m) {
      a[m][0] = *(const bf16x8*)(rdA + bo + m * 2048 + o0);
      a[m][1] = *(const bf16x8*)(rdA + bo + m * 2048 + o1);
    }
#pragma unroll
    for (int n = 0; n < 2; ++n) {
      b[n][0] = *(const bf16x8*)(rdB + bo + n * 2048 + o0);
      b[n][1] = *(const bf16x8*)(rdB + bo + n * 2048 + o1);
    }
    __builtin_amdgcn_s_setprio(1);
#pragma unroll
    for (int kk = 0; kk < 2; ++kk)
#pragma unroll
      for (int m = 0; m < 2; ++m)
#pragma unroll
        for (int n = 0; n < 2; ++n)
          acc[m][n] = __builtin_amdgcn_mfma_f32_32x32x16_bf16(a[m][kk], b[n][kk], acc[m][n], 0, 0, 0);
    __builtin_amdgcn_s_setprio(0);
    if (t + 3 < NK)      { WAITV(4); barrier_nodrain(); }
    else if (t + 2 < NK) { WAITV(2); barrier_nodrain(); }
    else if (t + 1 < NK) { WAITV(0); barrier_nodrain(); }
  }

  // epilogue: direct f32 store. C/D: col=la31, row=(reg&3)+8*(reg>>2)+4*kb
#pragma unroll
  for (int m = 0; m < 2; ++m)
#pragma unroll
    for (int n = 0; n < 2; ++n)
#pragma unroll
      for (int q = 0; q < 4; ++q)
#pragma unroll
        for (int jj = 0; jj < 4; ++jj) {
          const int row = m0 + wr * 64 + m * 32 + jj + 8 * q + 4 * kb;
          const int col = n0 + wc * 64 + n * 32 + la31;
          Out[(size_t)row * N + col] = acc[m][n][4 * q + jj];
        }
}

// ---------------------------------------------------------------------------
extern "C" void kernel_launch(void* const* d_in, const int* in_sizes, int n_in,
                              void* d_out, int out_size, void* d_ws, size_t ws_size,
                              hipStream_t stream) {
  const float* x  = (const float*)d_in[0];   // [2,2048,4096] -> [4096][4096]
  const float* w1 = (const float*)d_in[1];   // [11008,4096]
  const float* w2 = (const float*)d_in[2];   // [11008,4096]
  const float* w3 = (const float*)d_in[3];   // [4096,11008]
  float* out = (float*)d_out;

  char* ws = (char*)d_ws;
  unsigned short* xb  = (unsigned short*)(ws);                // 32 MiB
  unsigned short* w1b = (unsigned short*)(ws + 33554432);     // 86 MiB
  unsigned short* w2b = (unsigned short*)(ws + 123731968);    // 86 MiB
  unsigned short* hb  = (unsigned short*)(ws + 213909504);    // 86 MiB
  unsigned short* w3b = w1b;  // reuse after gemm1 (stream-ordered)

  const int NW = 11008 * 4096 / 4;
  k_f32_to_bf16<<<16384, 256, 0, stream>>>(x, xb, 4096 * 4096 / 4);
  k_dequant_nf4<<<NW / 256, 256, 0, stream>>>(w1, w1b, NW);
  k_dequant_nf4<<<NW / 256, 256, 0, stream>>>(w2, w2b, NW);

  // gate/up + SwiGLU -> h  (M=4096, N=11008, K=4096)
  k_gemm_dual_swiglu<<<1376, 1024, 0, stream>>>(xb, w1b, w2b, hb);

  k_dequant_nf4<<<NW / 256, 256, 0, stream>>>(w3, w3b, NW);

  // out = h . w3^T  (M=4096, N=4096, K=11008)
  k_gemm_out<<<256, 1024, 0, stream>>>(hb, w3b, out);
}